// Round 2
// baseline (257.303 us; speedup 1.0000x reference)
//
#include <hip/hip_runtime.h>
#include <hip/hip_bf16.h>

// Problem dims (fixed by reference)
#define BB 8
#define NN 2048
#define DD 256
#define MM (BB * NN)   // 16384 rows

typedef __attribute__((ext_vector_type(8))) short bf16x8_t;  // 8 bf16 = 4 VGPRs
typedef __attribute__((ext_vector_type(4))) float f32x4_t;

// ---------------------------------------------------------------------------
// Kernel A: h = x @ W^T + b. fp32 inputs, converted to bf16 at LDS staging,
// bf16 MFMA w/ fp32 accumulate, h written as bf16 (workspace).
// grid (M/64, 256/64), block 256 (4 waves).
// ---------------------------------------------------------------------------
__global__ __launch_bounds__(256) void gemm_h(
    const float* __restrict__ x,     // [M,256] fp32
    const float* __restrict__ Wt,    // [256,256] fp32 row-major [out,in] (B^T form)
    const float* __restrict__ bias,  // [256] fp32
    __hip_bfloat16* __restrict__ h)  // [M,256] bf16
{
    // pad leading dim to 72 bf16 (144 B = 16B-aligned rows)
    __shared__ __hip_bfloat16 As[64][72];
    __shared__ __hip_bfloat16 Bs[64][72];

    const int tid  = threadIdx.x;
    const int r    = tid >> 2;          // 0..63 staging row
    const int cs   = (tid & 3) * 16;    // k-segment 0/16/32/48
    const int w    = tid >> 6;          // wave 0..3
    const int lane = tid & 63;
    const int m16  = lane & 15;
    const int quad = lane >> 4;
    const long rowBase = (long)blockIdx.x * 64;
    const int  colBase = blockIdx.y * 64;

    f32x4_t acc[4];
#pragma unroll
    for (int c = 0; c < 4; c++) acc[c] = (f32x4_t){0.f, 0.f, 0.f, 0.f};

    for (int k0 = 0; k0 < 256; k0 += 64) {
        // load 16 fp32 of A-row and 16 fp32 of B-row per thread
        const float4* ag = (const float4*)(x  + (rowBase + r) * 256 + k0 + cs);
        const float4* bg = (const float4*)(Wt + (long)(colBase + r) * 256 + k0 + cs);
        float4 av[4], bv[4];
#pragma unroll
        for (int q = 0; q < 4; q++) { av[q] = ag[q]; bv[q] = bg[q]; }

        __align__(16) __hip_bfloat16 ta[16], tb[16];
#pragma unroll
        for (int q = 0; q < 4; q++) {
            ta[q * 4 + 0] = __float2bfloat16(av[q].x);
            ta[q * 4 + 1] = __float2bfloat16(av[q].y);
            ta[q * 4 + 2] = __float2bfloat16(av[q].z);
            ta[q * 4 + 3] = __float2bfloat16(av[q].w);
            tb[q * 4 + 0] = __float2bfloat16(bv[q].x);
            tb[q * 4 + 1] = __float2bfloat16(bv[q].y);
            tb[q * 4 + 2] = __float2bfloat16(bv[q].z);
            tb[q * 4 + 3] = __float2bfloat16(bv[q].w);
        }

        __syncthreads();  // previous iter's LDS reads done
        *(uint4*)&As[r][cs]     = *(uint4*)&ta[0];
        *(uint4*)&As[r][cs + 8] = *(uint4*)&ta[8];
        *(uint4*)&Bs[r][cs]     = *(uint4*)&tb[0];
        *(uint4*)&Bs[r][cs + 8] = *(uint4*)&tb[8];
        __syncthreads();

#pragma unroll
        for (int kk = 0; kk < 64; kk += 32) {
            bf16x8_t af = *(const bf16x8_t*)&As[w * 16 + m16][kk + quad * 8];
#pragma unroll
            for (int c = 0; c < 4; c++) {
                bf16x8_t bf = *(const bf16x8_t*)&Bs[c * 16 + m16][kk + quad * 8];
                acc[c] = __builtin_amdgcn_mfma_f32_16x16x32_bf16(af, bf, acc[c], 0, 0, 0);
            }
        }
    }

    // Epilogue: C/D layout col = lane&15 (N side), row = quad*4 + reg (M side)
#pragma unroll
    for (int c = 0; c < 4; c++) {
        const int col = colBase + c * 16 + m16;
        const float bv = bias[col];
#pragma unroll
        for (int reg = 0; reg < 4; reg++) {
            const long row = rowBase + w * 16 + quad * 4 + reg;
            h[row * 256 + col] = __float2bfloat16(acc[c][reg] + bv);
        }
    }
}

// ---------------------------------------------------------------------------
// Kernel B: s1 = h@a1, s2 = h@a2 per row (fp32). One wave per row.
// ---------------------------------------------------------------------------
struct __attribute__((aligned(8))) bf4 { __hip_bfloat16 v[4]; };

__global__ __launch_bounds__(256) void s_kernel(
    const __hip_bfloat16* __restrict__ h,
    const float* __restrict__ a1,
    const float* __restrict__ a2,
    float* __restrict__ s1, float* __restrict__ s2)
{
    const int w = threadIdx.x >> 6;
    const int lane = threadIdx.x & 63;
    const long row = (long)blockIdx.x * 4 + w;

    bf4 hv = *(const bf4*)(h + row * 256 + lane * 4);
    float4 A1 = *(const float4*)(a1 + lane * 4);
    float4 A2 = *(const float4*)(a2 + lane * 4);
    float p1 = 0.f, p2 = 0.f;
    const float h0 = __bfloat162float(hv.v[0]), h1 = __bfloat162float(hv.v[1]);
    const float h2 = __bfloat162float(hv.v[2]), h3 = __bfloat162float(hv.v[3]);
    p1 = h0 * A1.x + h1 * A1.y + h2 * A1.z + h3 * A1.w;
    p2 = h0 * A2.x + h1 * A2.y + h2 * A2.z + h3 * A2.w;
#pragma unroll
    for (int off = 32; off; off >>= 1) {
        p1 += __shfl_down(p1, off);
        p2 += __shfl_down(p2, off);
    }
    if (lane == 0) { s1[row] = p1; s2[row] = p2; }
}

// ---------------------------------------------------------------------------
// Kernel C: sparse attention aggregate. One block per (b,i) row.
// b = blockIdx & 7 -> batch<->XCD affinity keeps that batch's 1 MB bf16 h
// slice hot in the XCD's 4 MB L2.
// ---------------------------------------------------------------------------
__global__ __launch_bounds__(256) void attn_agg(
    const float* __restrict__ adj,
    const float* __restrict__ mask,
    const __hip_bfloat16* __restrict__ h,
    const float* __restrict__ s1,
    const float* __restrict__ s2,
    const float* __restrict__ attb_p,
    float* __restrict__ out)
{
    __shared__ unsigned short s_j[2048];
    __shared__ float s_w[2048];
    __shared__ int   s_cnt;
    __shared__ float s_red[4];
    __shared__ float s_inv;

    const int tid = threadIdx.x;
    const int b   = blockIdx.x & 7;
    const int i   = blockIdx.x >> 3;
    const long row = (long)b * NN + i;

    const float mask_i = mask[row];
    if (mask_i == 0.f) {                      // block-uniform branch
        out[row * 256 + tid] = 0.f;
        return;
    }
    if (tid == 0) s_cnt = 0;
    __syncthreads();

    const float si = s1[row] + attb_p[0];
    const long mbase = (long)b * NN;

    // scan this row's 2048 adj entries: 8 fp32 per thread (two 16B loads)
    const float4* arow = (const float4*)(adj + row * NN);
    float4 A0 = arow[tid * 2];
    float4 A1 = arow[tid * 2 + 1];
    float av[8] = {A0.x, A0.y, A0.z, A0.w, A1.x, A1.y, A1.z, A1.w};
    float lsum = 0.f;
#pragma unroll
    for (int e = 0; e < 8; e++) {
        if (av[e] != 0.f) {                   // adj entry nonzero (0.0 or 1.0)
            const int j = tid * 8 + e;
            const float mj = mask[mbase + j];
            if (mj != 0.f) {
                const float z = si + s2[mbase + j];
                const float wgt = av[e] * mj / (1.f + __expf(-z));
                const int pos = atomicAdd(&s_cnt, 1);
                s_j[pos] = (unsigned short)j;
                s_w[pos] = wgt;
                lsum += wgt;
            }
        }
    }

    // denominator: wave shuffle-reduce + cross-wave via LDS
#pragma unroll
    for (int off = 32; off; off >>= 1) lsum += __shfl_down(lsum, off);
    const int lane = tid & 63, w = tid >> 6;
    if (lane == 0) s_red[w] = lsum;
    __syncthreads();
    if (tid == 0) {
        const float t = s_red[0] + s_red[1] + s_red[2] + s_red[3];
        s_inv = 1.f / (t + 1e-8f);
    }
    __syncthreads();

    const int cnt = s_cnt;
    const float inv = s_inv;
    const __hip_bfloat16* hb = h + mbase * 256 + tid;  // thread owns channel d = tid
    float acc = 0.f;
    int k = 0;
    for (; k + 4 <= cnt; k += 4) {            // 4 independent loads in flight
        const int j0 = s_j[k], j1 = s_j[k + 1], j2 = s_j[k + 2], j3 = s_j[k + 3];
        const float w0 = s_w[k], w1 = s_w[k + 1], w2 = s_w[k + 2], w3 = s_w[k + 3];
        const float g0 = __bfloat162float(hb[(long)j0 * 256]);
        const float g1 = __bfloat162float(hb[(long)j1 * 256]);
        const float g2 = __bfloat162float(hb[(long)j2 * 256]);
        const float g3 = __bfloat162float(hb[(long)j3 * 256]);
        acc += w0 * g0 + w1 * g1 + w2 * g2 + w3 * g3;
    }
    for (; k < cnt; k++)
        acc += s_w[k] * __bfloat162float(hb[(long)s_j[k] * 256]);

    out[row * 256 + tid] = acc * inv;
}

// ---------------------------------------------------------------------------
extern "C" void kernel_launch(void* const* d_in, const int* in_sizes, int n_in,
                              void* d_out, int out_size, void* d_ws, size_t ws_size,
                              hipStream_t stream) {
    const float* x    = (const float*)d_in[0];
    const float* adj  = (const float*)d_in[1];
    const float* mask = (const float*)d_in[2];
    const float* W    = (const float*)d_in[3];
    const float* bias = (const float*)d_in[4];
    const float* a1   = (const float*)d_in[5];
    const float* a2   = (const float*)d_in[6];
    const float* attb = (const float*)d_in[7];
    float* out = (float*)d_out;

    // workspace layout: h bf16 [16384*256] (8 MB) | s1 fp32 [16384] | s2 fp32 [16384]
    __hip_bfloat16* h = (__hip_bfloat16*)d_ws;
    float* s1 = (float*)((char*)d_ws + (size_t)MM * DD * 2);
    float* s2 = s1 + MM;

    gemm_h<<<dim3(MM / 64, DD / 64), 256, 0, stream>>>(x, W, bias, h);
    s_kernel<<<MM / 4, 256, 0, stream>>>(h, a1, a2, s1, s2);
    attn_agg<<<MM, 256, 0, stream>>>(adj, mask, h, s1, s2, attb, out);
}